// Round 15
// baseline (171.869 us; speedup 1.0000x reference)
//
#include <hip/hip_runtime.h>
#include <hip/hip_bf16.h>

// Problem constants
static constexpr int B   = 4;
static constexpr int N   = 16384;   // 2^14
static constexpr int E   = 131072;  // 2^17
static constexpr int C   = 128;
static constexpr int ND  = 3;
static constexpr int MID = 128;
static constexpr int OUT = 128;
static constexpr int K1  = C * ND;  // 384
static constexpr int NT  = 32;      // nodes per block in fused grad+MLP
static constexpr int K1P = 392;     // padded LDS row

typedef __attribute__((ext_vector_type(8))) short bf16x8;
typedef __attribute__((ext_vector_type(4))) float f32x4;

__device__ __forceinline__ ushort f2bf(float x) {
    union { float f; unsigned u; } v; v.f = x;
    return (ushort)((v.u + 0x7fffu + ((v.u >> 16) & 1u)) >> 16);  // RNE
}
__device__ __forceinline__ float bf2f(ushort u) {
    union { unsigned u; float f; } v; v.u = (unsigned)u << 16;
    return v.f;
}

// ---------------- fused front: transpose | count | weight-prep ----------------
__global__ void k_front(const float* __restrict__ f, ushort* __restrict__ fT,
                        const int2* __restrict__ ei2, int* __restrict__ deg,
                        const float* __restrict__ W1, const float* __restrict__ W2,
                        const float* __restrict__ L, ushort* __restrict__ W1p,
                        ushort* __restrict__ W2p, float* __restrict__ Sig) {
    __shared__ float tile[32][33];
    int bid = blockIdx.x, tid = threadIdx.x;  // 256 threads
    if (bid < 8192) {
        int bx = bid & 511, by = (bid >> 9) & 3, b = bid >> 11;
        int n0 = bx * 32, c0 = by * 32;
        const float* fb = f + (size_t)b * C * N;
        ushort* fTb = fT + (size_t)b * N * C;
        int tx = tid & 31, ty = tid >> 5;
        #pragma unroll
        for (int i = 0; i < 32; i += 8)
            tile[ty + i][tx] = fb[(size_t)(c0 + ty + i) * N + n0 + tx];
        __syncthreads();
        #pragma unroll
        for (int i = 0; i < 32; i += 8)
            fTb[(size_t)(n0 + ty + i) * C + c0 + tx] = f2bf(tile[tx][ty + i]);
    } else if (bid < 10240) {
        int idx = (bid - 8192) * 256 + tid;  // 0..B*E-1
        int b = idx >> 17;
        int tgt = ei2[idx].y;
        atomicAdd(&deg[b * N + tgt], 1);
    } else {
        int gid = (bid - 10240) * 256 + tid;  // 0..16383
        for (int i = gid; i < 8 * 12 * 64 * 8; i += 64 * 256) {
            int j = i & 7, l = (i >> 3) & 63, t = (i >> 9) % 12, nt = (i >> 9) / 12;
            int n = nt * 16 + (l & 15);
            int k = t * 32 + ((l >> 4) & 3) * 8 + j;
            W1p[i] = f2bf(W1[n * K1 + k]);
        }
        {
            int i = gid;  // 16384 elements, one per thread
            int j = i & 7, l = (i >> 3) & 63, t = (i >> 9) % 4, nt = (i >> 9) / 4;
            int n = nt * 16 + (l & 15);
            int k = t * 32 + ((l >> 4) & 3) * 8 + j;
            W2p[i] = f2bf(W2[n * MID + k]);
        }
        if (gid < 9) {
            int i = gid / 3, j = gid % 3;
            Sig[gid] = L[i * 3 + 0] * L[j * 3 + 0] + L[i * 3 + 1] * L[j * 3 + 1] +
                       L[i * 3 + 2] * L[j * 3 + 2];
        }
    }
}

// ---------------- hierarchical exclusive scan over 65536 ints ----------------
__global__ void k_scan1(const int4* __restrict__ degv, int* __restrict__ rowptr,
                        int* __restrict__ bsum) {
    __shared__ int s[256];
    int blk = blockIdx.x, t = threadIdx.x;
    int4 d = degv[blk * 256 + t];
    s[t] = d.x + d.y + d.z + d.w;
    __syncthreads();
    for (int off = 1; off < 256; off <<= 1) {
        int v = s[t];
        int u = (t >= off) ? s[t - off] : 0;
        __syncthreads();
        s[t] = v + u;
        __syncthreads();
    }
    int excl = (t == 0) ? 0 : s[t - 1];
    if (t == 255) bsum[blk] = s[255];
    int4 w;
    w.x = excl;
    w.y = excl + d.x;
    w.z = w.y + d.y;
    w.w = w.z + d.z;
    ((int4*)rowptr)[blk * 256 + t] = w;
}

__global__ void k_scan2(int* __restrict__ bsum, int* __restrict__ rowptr) {
    __shared__ int s[64];
    int t = threadIdx.x;  // 64
    s[t] = bsum[t];
    __syncthreads();
    for (int off = 1; off < 64; off <<= 1) {
        int v = s[t];
        int u = (t >= off) ? s[t - off] : 0;
        __syncthreads();
        s[t] = v + u;
        __syncthreads();
    }
    bsum[t] = (t == 0) ? 0 : s[t - 1];
    if (t == 63) rowptr[B * N] = s[63];
}

__global__ void k_scan3(int4* __restrict__ rowv, const int* __restrict__ bsum) {
    int i = blockIdx.x * 256 + threadIdx.x;  // 0..16383 (int4 index)
    int add = bsum[i >> 8];
    int4 v = rowv[i];
    v.x += add; v.y += add; v.z += add; v.w += add;
    rowv[i] = v;
}

// ---------------- CSR fill pass 1: scatter edge id (4B) ----------------
__global__ void k_fill_perm(const int2* __restrict__ ei2,
                            const int* __restrict__ rowptr,
                            int* __restrict__ cursor, int* __restrict__ perm) {
    int idx = blockIdx.x * 256 + threadIdx.x;
    int b = idx >> 17;
    int tgt = ei2[idx].y;
    int bn = b * N + tgt;
    int pos = atomicAdd(&cursor[bn], 1);
    perm[rowptr[bn] + pos] = idx;
}

// ---------------- CSR fill pass 2: coalesced expand (egwp, ka2) ----------------
__global__ void k_fill_expand(const int* __restrict__ perm,
                              const int2* __restrict__ ei2,
                              const float* __restrict__ egw,
                              const float* __restrict__ nodes,
                              const float* __restrict__ nw,
                              const float* __restrict__ Sig,
                              const float* __restrict__ cb,
                              float4* __restrict__ egwp, float2* __restrict__ ka2) {
    int o = blockIdx.x * 256 + threadIdx.x;
    int idx = perm[o];
    int b = idx >> 17;
    int2 e = ei2[idx];
    int src = e.x, tgt = e.y;
    const float* w = egw + (size_t)idx * ND;
    egwp[o] = make_float4(w[0], w[1], w[2], __int_as_float(src));
    const float* ns = nodes + ((size_t)b * N + src) * ND;
    const float* nt = nodes + ((size_t)b * N + tgt) * ND;
    float d0 = ns[0] - nt[0], d1 = ns[1] - nt[1], d2 = ns[2] - nt[2];
    float q = d0 * (Sig[0] * d0 + Sig[1] * d1 + Sig[2] * d2) +
              d1 * (Sig[3] * d0 + Sig[4] * d1 + Sig[5] * d2) +
              d2 * (Sig[6] * d0 + Sig[7] * d1 + Sig[8] * d2) +
              d0 * cb[0] + d1 * cb[1] + d2 * cb[2];
    ka2[o] = make_float2(nw[(size_t)b * N + src] * expf(-q), __int_as_float(src));
}

// Per-edge gather FMA: round-7 form, verbatim (empirically 4.88e-4 stable).
#define EDGE_FMA(W, U)                                                         \
    {                                                                          \
        float dx = bf2f(U.x) - ft.x, dy = bf2f(U.y) - ft.y,                    \
              dz = bf2f(U.z) - ft.z, dw = bf2f(U.w) - ft.w;                    \
        a0.x = fmaf(dx, W.x, a0.x); a0.y = fmaf(dy, W.x, a0.y);                \
        a0.z = fmaf(dz, W.x, a0.z); a0.w = fmaf(dw, W.x, a0.w);                \
        a1.x = fmaf(dx, W.y, a1.x); a1.y = fmaf(dy, W.y, a1.y);                \
        a1.z = fmaf(dz, W.y, a1.z); a1.w = fmaf(dw, W.y, a1.w);                \
        a2.x = fmaf(dx, W.z, a2.x); a2.y = fmaf(dy, W.z, a2.y);                \
        a2.z = fmaf(dz, W.z, a2.z); a2.w = fmaf(dw, W.z, a2.w);                \
    }

// ---------------- fused gradient gather (VALU) + pointwise MLP (MFMA) --------
// Gather: 32-lane/float4 numeric path (verbatim accumulation order), with a
// 1-deep software pipeline on the edge-record loads ONLY: fT-row loads issue
// immediately at quantum top (w regs ready from last iter); next quantum's
// egwp records fetched (clamped in-bounds) while FMAs consume current rows.
// Bit-identical values; only load timing changes. Work-stealing node queue.
__global__ __launch_bounds__(512, 5) void k_grad_mlp(
    const ushort* __restrict__ fT, const int* __restrict__ rowptr,
    const float4* __restrict__ egwp, const ushort* __restrict__ W1p,
    const float* __restrict__ b1, const ushort* __restrict__ W2p,
    const float* __restrict__ b2, ushort* __restrict__ fo) {
    __shared__ ushort g_s[NT][K1P];  // 25088 B
    __shared__ int ctr;
    int tid = threadIdx.x;
    int bid = blockIdx.x;
    int swz = (bid & 7) * ((B * N / NT) >> 3) + (bid >> 3);  // XCD swizzle
    int n0 = swz * NT;  // flat node over B*N

    if (tid == 0) ctr = 0;
    __syncthreads();

    {  // ---- gather phase (work-stealing over NT nodes, 16 slots x 32 lanes) ----
        int cg = tid & 31;
        int cg4 = cg * 4;
        bool lane0 = (cg == 0);
        for (;;) {
            int j;
            if (lane0) j = atomicAdd(&ctr, 1);
            j = __shfl(j, 0, 32);  // broadcast from slot's lane 0
            if (j >= NT) break;
            int n = n0 + j;
            const ushort* fTb = fT + (size_t)(n >> 14) * N * C;  // batch base
            float4 ft;
            {
                ushort4 u = *(const ushort4*)(fT + (size_t)n * C + cg4);
                ft = make_float4(bf2f(u.x), bf2f(u.y), bf2f(u.z), bf2f(u.w));
            }
            int base = rowptr[n], cnt = rowptr[n + 1] - base;
            float4 a0 = make_float4(0.f, 0.f, 0.f, 0.f), a1 = a0, a2 = a0;
            float4 wA, wB, wC, wD;
            if (cnt >= 4) {
                wA = egwp[base];     wB = egwp[base + 1];
                wC = egwp[base + 2]; wD = egwp[base + 3];
            }
            int i = 0;
            while (i + 4 <= cnt) {
                ushort4 u0 = *(const ushort4*)(fTb + (size_t)__float_as_int(wA.w) * C + cg4);
                ushort4 u1 = *(const ushort4*)(fTb + (size_t)__float_as_int(wB.w) * C + cg4);
                ushort4 u2 = *(const ushort4*)(fTb + (size_t)__float_as_int(wC.w) * C + cg4);
                ushort4 u3 = *(const ushort4*)(fTb + (size_t)__float_as_int(wD.w) * C + cg4);
                i += 4;
                int ip = (i + 4 <= cnt) ? i : (i - 4);  // clamped (in-bounds) prefetch
                float4 nA = egwp[base + ip];
                float4 nB = egwp[base + ip + 1];
                float4 nC = egwp[base + ip + 2];
                float4 nD = egwp[base + ip + 3];
                EDGE_FMA(wA, u0); EDGE_FMA(wB, u1);
                EDGE_FMA(wC, u2); EDGE_FMA(wD, u3);
                wA = nA; wB = nB; wC = nC; wD = nD;
            }
            for (; i < cnt; ++i) {
                float4 w0 = egwp[base + i];
                ushort4 u0 = *(const ushort4*)(fTb + (size_t)__float_as_int(w0.w) * C + cg4);
                EDGE_FMA(w0, u0);
            }
            // g[k], k = c*3+d, c = 4cg+u -> k = 12cg+3u+d: 12 contiguous bf16
            unsigned p0 = (unsigned)f2bf(a0.x) | ((unsigned)f2bf(a1.x) << 16);
            unsigned p1 = (unsigned)f2bf(a2.x) | ((unsigned)f2bf(a0.y) << 16);
            unsigned p2 = (unsigned)f2bf(a1.y) | ((unsigned)f2bf(a2.y) << 16);
            unsigned p3 = (unsigned)f2bf(a0.z) | ((unsigned)f2bf(a1.z) << 16);
            unsigned p4 = (unsigned)f2bf(a2.z) | ((unsigned)f2bf(a0.w) << 16);
            unsigned p5 = (unsigned)f2bf(a1.w) | ((unsigned)f2bf(a2.w) << 16);
            uint2* dst = (uint2*)&g_s[j][cg * 12];
            dst[0] = make_uint2(p0, p1);
            dst[1] = make_uint2(p2, p3);
            dst[2] = make_uint2(p4, p5);
        }
    }
    __syncthreads();

    // ---- MFMA phase: 8 waves = 2 mtiles x 4 nt-pairs ----
    int wv = tid >> 6, ln = tid & 63, lr = ln & 15, lh = ln >> 4;
    int mt = wv & 1, nh = wv >> 1;
    bf16x8 a[12];  // A-frags for this wave's 16-node mtile, all K
    {
        const ushort* grow = &g_s[mt * 16 + lr][0];
        #pragma unroll
        for (int t = 0; t < 12; ++t)
            a[t] = *(const bf16x8*)(grow + t * 32 + lh * 8);
    }
    __syncthreads();  // all A-reads done before h_s (aliasing g_s) is written

    ushort(*h_s)[136] = (ushort(*)[136]) & g_s[0][0];  // 8704 B alias
    const bf16x8* W1f = (const bf16x8*)W1p;
    #pragma unroll
    for (int q = 0; q < 2; ++q) {
        int nt = nh * 2 + q;
        float bb = b1[nt * 16 + lr];
        f32x4 c = {bb, bb, bb, bb};
        #pragma unroll
        for (int t = 0; t < 12; ++t)
            c = __builtin_amdgcn_mfma_f32_16x16x32_bf16(
                a[t], W1f[(nt * 12 + t) * 64 + ln], c, 0, 0, 0);
        #pragma unroll
        for (int r = 0; r < 4; ++r) {
            float x = c[r];
            x = 0.5f * x * (1.0f + erff(x * 0.70710678118654752f));
            h_s[mt * 16 + lh * 4 + r][nt * 16 + lr] = f2bf(x);  // row=node, col=mid
        }
    }
    __syncthreads();  // all nt-pairs of h complete

    bf16x8 a2[4];
    {
        const ushort* hrow = &h_s[mt * 16 + lr][0];
        #pragma unroll
        for (int t = 0; t < 4; ++t)
            a2[t] = *(const bf16x8*)(hrow + t * 32 + lh * 8);
    }
    const bf16x8* W2f = (const bf16x8*)W2p;
    #pragma unroll
    for (int q = 0; q < 2; ++q) {
        int nt = nh * 2 + q;
        float bb = b2[nt * 16 + lr];
        f32x4 c = {bb, bb, bb, bb};
        #pragma unroll
        for (int t = 0; t < 4; ++t)
            c = __builtin_amdgcn_mfma_f32_16x16x32_bf16(
                a2[t], W2f[(nt * 4 + t) * 64 + ln], c, 0, 0, 0);
        #pragma unroll
        for (int r = 0; r < 4; ++r)
            fo[(size_t)(n0 + mt * 16 + lh * 4 + r) * OUT + nt * 16 + lr] = f2bf(c[r]);
    }
}

#define AGG_FMA(K, U)                                                          \
    {                                                                          \
        o.x = fmaf(bf2f(U.x), K.x, o.x); o.y = fmaf(bf2f(U.y), K.x, o.y);      \
        o.z = fmaf(bf2f(U.z), K.x, o.z); o.w = fmaf(bf2f(U.w), K.x, o.w);      \
        den += K.x;                                                            \
    }

// ---------------- edge aggregation (CSR gather) + normalize + fused transpose ----
// Same 1-deep ka2 prefetch pipeline; per-node loop otherwise verbatim.
__global__ __launch_bounds__(512, 5) void k_agg_t(const ushort* __restrict__ fo,
                                                  const float* __restrict__ nw,
                                                  const int* __restrict__ rowptr,
                                                  const float2* __restrict__ ka2,
                                                  float* __restrict__ out) {
    __shared__ float t[OUT][65];
    __shared__ int ctr;
    int tid = threadIdx.x;
    int cg = tid & 31;
    int cg4 = cg * 4;
    bool lane0 = (cg == 0);
    int bid = blockIdx.x;
    int swz = (bid & 7) * ((B * N / 64) >> 3) + (bid >> 3);  // XCD swizzle
    int n0 = swz * 64;                // flat node over B*N
    int b = n0 >> 14, ncol0 = n0 & (N - 1);
    const ushort* fob = fo + (size_t)b * N * OUT;

    if (tid == 0) ctr = 0;
    __syncthreads();

    for (;;) {
        int nl;
        if (lane0) nl = atomicAdd(&ctr, 1);
        nl = __shfl(nl, 0, 32);
        if (nl >= 64) break;
        int n = n0 + nl;
        int base = rowptr[n], cnt = rowptr[n + 1] - base;
        float4 o = make_float4(0.f, 0.f, 0.f, 0.f);
        float den = 0.f;
        float2 kA, kB, kC, kD;
        if (cnt >= 4) {
            kA = ka2[base];     kB = ka2[base + 1];
            kC = ka2[base + 2]; kD = ka2[base + 3];
        }
        int i = 0;
        while (i + 4 <= cnt) {
            ushort4 u0 = *(const ushort4*)(fob + (size_t)__float_as_int(kA.y) * OUT + cg4);
            ushort4 u1 = *(const ushort4*)(fob + (size_t)__float_as_int(kB.y) * OUT + cg4);
            ushort4 u2 = *(const ushort4*)(fob + (size_t)__float_as_int(kC.y) * OUT + cg4);
            ushort4 u3 = *(const ushort4*)(fob + (size_t)__float_as_int(kD.y) * OUT + cg4);
            i += 4;
            int ip = (i + 4 <= cnt) ? i : (i - 4);  // clamped (in-bounds) prefetch
            float2 nA = ka2[base + ip];
            float2 nB = ka2[base + ip + 1];
            float2 nC = ka2[base + ip + 2];
            float2 nD = ka2[base + ip + 3];
            AGG_FMA(kA, u0);
            AGG_FMA(kB, u1);
            AGG_FMA(kC, u2);
            AGG_FMA(kD, u3);
            kA = nA; kB = nB; kC = nC; kD = nD;
        }
        for (; i < cnt; ++i) {
            float2 k0 = ka2[base + i];
            ushort4 u0 = *(const ushort4*)(fob + (size_t)__float_as_int(k0.y) * OUT + cg4);
            AGG_FMA(k0, u0);
        }
        float wn = nw[n];  // self edge: d=0 -> kern = nw[n]
        ushort4 uf = *(const ushort4*)(fo + (size_t)n * OUT + cg4);
        float inv = 1.f / (den + wn);
        t[cg4 + 0][nl] = (o.x + bf2f(uf.x) * wn) * inv;
        t[cg4 + 1][nl] = (o.y + bf2f(uf.y) * wn) * inv;
        t[cg4 + 2][nl] = (o.z + bf2f(uf.z) * wn) * inv;
        t[cg4 + 3][nl] = (o.w + bf2f(uf.w) * wn) * inv;
    }
    __syncthreads();
    #pragma unroll
    for (int i = 0; i < 16; ++i) {
        int idx = tid + i * 512;
        int o = idx >> 6, nl = idx & 63;  // nl fastest -> coalesced writes
        out[((size_t)b * OUT + o) * N + ncol0 + nl] = t[o][nl];
    }
}

extern "C" void kernel_launch(void* const* d_in, const int* in_sizes, int n_in,
                              void* d_out, int out_size, void* d_ws, size_t ws_size,
                              hipStream_t stream) {
    const float* f     = (const float*)d_in[0];
    const float* nodes = (const float*)d_in[1];
    const float* nw    = (const float*)d_in[2];
    const int*   ei    = (const int*)d_in[3];
    const float* egw   = (const float*)d_in[4];
    const float* W1    = (const float*)d_in[5];
    const float* b1    = (const float*)d_in[6];
    const float* W2    = (const float*)d_in[7];
    const float* b2    = (const float*)d_in[8];
    const float* L     = (const float*)d_in[9];
    const float* cb    = (const float*)d_in[10];
    float* out = (float*)d_out;

    char* ws = (char*)d_ws;
    auto alloc = [&](size_t bytes) {
        void* p = ws;
        ws += (bytes + 255) & ~(size_t)255;
        return p;
    };
    ushort* fT     = (ushort*)alloc((size_t)B * N * C * 2);
    ushort* fo     = (ushort*)alloc((size_t)B * N * OUT * 2);  // bf16 (R7-proven)
    ushort* W1p    = (ushort*)alloc((size_t)MID * K1 * 2);
    ushort* W2p    = (ushort*)alloc((size_t)OUT * MID * 2);
    float*  Sig    = (float*)alloc(16 * 4);
    int*    deg    = (int*)alloc((size_t)B * N * 4);   // contiguous with cursor:
    int*    cursor = (int*)alloc((size_t)B * N * 4);   // one memset covers both
    int*    rowptr = (int*)alloc(((size_t)B * N + 4) * 4);
    int*    bsum   = (int*)alloc(64 * 4);
    int*    perm   = (int*)alloc((size_t)B * E * 4);
    float4* egwp   = (float4*)alloc((size_t)B * E * 16);
    float2* ka2    = (float2*)alloc((size_t)B * E * 8);

    hipMemsetAsync(deg, 0, (size_t)B * N * 4 * 2, stream);  // deg + cursor

    k_front<<<10304, 256, 0, stream>>>(f, fT, (const int2*)ei, deg, W1, W2, L,
                                       W1p, W2p, Sig);
    k_scan1<<<64, 256, 0, stream>>>((const int4*)deg, rowptr, bsum);
    k_scan2<<<1, 64, 0, stream>>>(bsum, rowptr);
    k_scan3<<<64, 256, 0, stream>>>((int4*)rowptr, bsum);
    k_fill_perm<<<(B * E) / 256, 256, 0, stream>>>((const int2*)ei, rowptr, cursor,
                                                   perm);
    k_fill_expand<<<(B * E) / 256, 256, 0, stream>>>(perm, (const int2*)ei, egw,
                                                     nodes, nw, Sig, cb, egwp, ka2);
    k_grad_mlp<<<(B * N) / NT, 512, 0, stream>>>(fT, rowptr, egwp, W1p, b1, W2p,
                                                 b2, fo);
    k_agg_t<<<(B * N) / 64, 512, 0, stream>>>(fo, nw, rowptr, ka2, out);
}

// Round 16
// 161.588 us; speedup vs baseline: 1.0636x; 1.0636x over previous
//
#include <hip/hip_runtime.h>
#include <hip/hip_bf16.h>

// Problem constants
static constexpr int B   = 4;
static constexpr int N   = 16384;   // 2^14
static constexpr int E   = 131072;  // 2^17
static constexpr int C   = 128;
static constexpr int ND  = 3;
static constexpr int MID = 128;
static constexpr int OUT = 128;
static constexpr int K1  = C * ND;  // 384
static constexpr int NTG = 16;      // nodes per block, fused grad+MLP (256 thr)
static constexpr int NTA = 32;      // nodes per block, agg (256 thr)
static constexpr int K1P = 392;     // padded LDS row

typedef __attribute__((ext_vector_type(8))) short bf16x8;
typedef __attribute__((ext_vector_type(4))) float f32x4;

__device__ __forceinline__ ushort f2bf(float x) {
    union { float f; unsigned u; } v; v.f = x;
    return (ushort)((v.u + 0x7fffu + ((v.u >> 16) & 1u)) >> 16);  // RNE
}
__device__ __forceinline__ float bf2f(ushort u) {
    union { unsigned u; float f; } v; v.u = (unsigned)u << 16;
    return v.f;
}

// ---------------- fused front: transpose | count | weight-prep ----------------
__global__ void k_front(const float* __restrict__ f, ushort* __restrict__ fT,
                        const int2* __restrict__ ei2, int* __restrict__ deg,
                        const float* __restrict__ W1, const float* __restrict__ W2,
                        const float* __restrict__ L, ushort* __restrict__ W1p,
                        ushort* __restrict__ W2p, float* __restrict__ Sig) {
    __shared__ float tile[32][33];
    int bid = blockIdx.x, tid = threadIdx.x;  // 256 threads
    if (bid < 8192) {
        int bx = bid & 511, by = (bid >> 9) & 3, b = bid >> 11;
        int n0 = bx * 32, c0 = by * 32;
        const float* fb = f + (size_t)b * C * N;
        ushort* fTb = fT + (size_t)b * N * C;
        int tx = tid & 31, ty = tid >> 5;
        #pragma unroll
        for (int i = 0; i < 32; i += 8)
            tile[ty + i][tx] = fb[(size_t)(c0 + ty + i) * N + n0 + tx];
        __syncthreads();
        #pragma unroll
        for (int i = 0; i < 32; i += 8)
            fTb[(size_t)(n0 + ty + i) * C + c0 + tx] = f2bf(tile[tx][ty + i]);
    } else if (bid < 10240) {
        int idx = (bid - 8192) * 256 + tid;  // 0..B*E-1
        int b = idx >> 17;
        int tgt = ei2[idx].y;
        atomicAdd(&deg[b * N + tgt], 1);
    } else {
        int gid = (bid - 10240) * 256 + tid;  // 0..16383
        for (int i = gid; i < 8 * 12 * 64 * 8; i += 64 * 256) {
            int j = i & 7, l = (i >> 3) & 63, t = (i >> 9) % 12, nt = (i >> 9) / 12;
            int n = nt * 16 + (l & 15);
            int k = t * 32 + ((l >> 4) & 3) * 8 + j;
            W1p[i] = f2bf(W1[n * K1 + k]);
        }
        {
            int i = gid;  // 16384 elements, one per thread
            int j = i & 7, l = (i >> 3) & 63, t = (i >> 9) % 4, nt = (i >> 9) / 4;
            int n = nt * 16 + (l & 15);
            int k = t * 32 + ((l >> 4) & 3) * 8 + j;
            W2p[i] = f2bf(W2[n * MID + k]);
        }
        if (gid < 9) {
            int i = gid / 3, j = gid % 3;
            Sig[gid] = L[i * 3 + 0] * L[j * 3 + 0] + L[i * 3 + 1] * L[j * 3 + 1] +
                       L[i * 3 + 2] * L[j * 3 + 2];
        }
    }
}

// ---------------- hierarchical exclusive scan over 65536 ints ----------------
__global__ void k_scan1(const int4* __restrict__ degv, int* __restrict__ rowptr,
                        int* __restrict__ bsum) {
    __shared__ int s[256];
    int blk = blockIdx.x, t = threadIdx.x;
    int4 d = degv[blk * 256 + t];
    s[t] = d.x + d.y + d.z + d.w;
    __syncthreads();
    for (int off = 1; off < 256; off <<= 1) {
        int v = s[t];
        int u = (t >= off) ? s[t - off] : 0;
        __syncthreads();
        s[t] = v + u;
        __syncthreads();
    }
    int excl = (t == 0) ? 0 : s[t - 1];
    if (t == 255) bsum[blk] = s[255];
    int4 w;
    w.x = excl;
    w.y = excl + d.x;
    w.z = w.y + d.y;
    w.w = w.z + d.z;
    ((int4*)rowptr)[blk * 256 + t] = w;
}

__global__ void k_scan2(int* __restrict__ bsum, int* __restrict__ rowptr) {
    __shared__ int s[64];
    int t = threadIdx.x;  // 64
    s[t] = bsum[t];
    __syncthreads();
    for (int off = 1; off < 64; off <<= 1) {
        int v = s[t];
        int u = (t >= off) ? s[t - off] : 0;
        __syncthreads();
        s[t] = v + u;
        __syncthreads();
    }
    bsum[t] = (t == 0) ? 0 : s[t - 1];
    if (t == 63) rowptr[B * N] = s[63];
}

__global__ void k_scan3(int4* __restrict__ rowv, const int* __restrict__ bsum) {
    int i = blockIdx.x * 256 + threadIdx.x;  // 0..16383 (int4 index)
    int add = bsum[i >> 8];
    int4 v = rowv[i];
    v.x += add; v.y += add; v.z += add; v.w += add;
    rowv[i] = v;
}

// ---------------- CSR fill pass 1: scatter edge id (4B) ----------------
__global__ void k_fill_perm(const int2* __restrict__ ei2,
                            const int* __restrict__ rowptr,
                            int* __restrict__ cursor, int* __restrict__ perm) {
    int idx = blockIdx.x * 256 + threadIdx.x;
    int b = idx >> 17;
    int tgt = ei2[idx].y;
    int bn = b * N + tgt;
    int pos = atomicAdd(&cursor[bn], 1);
    perm[rowptr[bn] + pos] = idx;
}

// ---------------- CSR fill pass 2: coalesced expand (egwp, ka2) ----------------
__global__ void k_fill_expand(const int* __restrict__ perm,
                              const int2* __restrict__ ei2,
                              const float* __restrict__ egw,
                              const float* __restrict__ nodes,
                              const float* __restrict__ nw,
                              const float* __restrict__ Sig,
                              const float* __restrict__ cb,
                              float4* __restrict__ egwp, float2* __restrict__ ka2) {
    int o = blockIdx.x * 256 + threadIdx.x;
    int idx = perm[o];
    int b = idx >> 17;
    int2 e = ei2[idx];
    int src = e.x, tgt = e.y;
    const float* w = egw + (size_t)idx * ND;
    egwp[o] = make_float4(w[0], w[1], w[2], __int_as_float(src));
    const float* ns = nodes + ((size_t)b * N + src) * ND;
    const float* nt = nodes + ((size_t)b * N + tgt) * ND;
    float d0 = ns[0] - nt[0], d1 = ns[1] - nt[1], d2 = ns[2] - nt[2];
    float q = d0 * (Sig[0] * d0 + Sig[1] * d1 + Sig[2] * d2) +
              d1 * (Sig[3] * d0 + Sig[4] * d1 + Sig[5] * d2) +
              d2 * (Sig[6] * d0 + Sig[7] * d1 + Sig[8] * d2) +
              d0 * cb[0] + d1 * cb[1] + d2 * cb[2];
    ka2[o] = make_float2(nw[(size_t)b * N + src] * expf(-q), __int_as_float(src));
}

// Per-edge gather FMA: round-7 form, verbatim (empirically 4.88e-4 stable).
#define EDGE_FMA(W, U)                                                         \
    {                                                                          \
        float dx = bf2f(U.x) - ft.x, dy = bf2f(U.y) - ft.y,                    \
              dz = bf2f(U.z) - ft.z, dw = bf2f(U.w) - ft.w;                    \
        a0.x = fmaf(dx, W.x, a0.x); a0.y = fmaf(dy, W.x, a0.y);                \
        a0.z = fmaf(dz, W.x, a0.z); a0.w = fmaf(dw, W.x, a0.w);                \
        a1.x = fmaf(dx, W.y, a1.x); a1.y = fmaf(dy, W.y, a1.y);                \
        a1.z = fmaf(dz, W.y, a1.z); a1.w = fmaf(dw, W.y, a1.w);                \
        a2.x = fmaf(dx, W.z, a2.x); a2.y = fmaf(dy, W.z, a2.y);                \
        a2.z = fmaf(dz, W.z, a2.z); a2.w = fmaf(dw, W.z, a2.w);                \
    }

#define EDGE_LOAD(K)                                                           \
    float4 w##K = egwp[base + i + K];                                          \
    ushort4 u##K = *(const ushort4*)(fTb + (size_t)__float_as_int(w##K.w) * C + cg4);

// ---------------- fused gradient gather (VALU) + pointwise MLP (MFMA) --------
// R14 inner loop verbatim (compiler-scheduled unroll 4->1; R13 unroll-8 and
// R15 manual pipeline both regressed it). Geometry change only: NTG=16 nodes,
// 256 threads -> LDS 12.5KB -> 8 blocks/CU (was 4), finer barrier scope.
__global__ __launch_bounds__(256, 5) void k_grad_mlp(
    const ushort* __restrict__ fT, const int* __restrict__ rowptr,
    const float4* __restrict__ egwp, const ushort* __restrict__ W1p,
    const float* __restrict__ b1, const ushort* __restrict__ W2p,
    const float* __restrict__ b2, ushort* __restrict__ fo) {
    __shared__ ushort g_s[NTG][K1P];  // 12544 B
    __shared__ int ctr;
    int tid = threadIdx.x;
    int bid = blockIdx.x;
    int swz = (bid & 7) * ((B * N / NTG) >> 3) + (bid >> 3);  // XCD swizzle
    int n0 = swz * NTG;  // flat node over B*N

    if (tid == 0) ctr = 0;
    __syncthreads();

    {  // ---- gather phase (work-stealing over NTG nodes, 8 slots x 32 lanes) ----
        int cg = tid & 31;
        int cg4 = cg * 4;
        bool lane0 = (cg == 0);
        for (;;) {
            int j;
            if (lane0) j = atomicAdd(&ctr, 1);
            j = __shfl(j, 0, 32);  // broadcast from slot's lane 0
            if (j >= NTG) break;
            int n = n0 + j;
            const ushort* fTb = fT + (size_t)(n >> 14) * N * C;  // batch base
            float4 ft;
            {
                ushort4 u = *(const ushort4*)(fT + (size_t)n * C + cg4);
                ft = make_float4(bf2f(u.x), bf2f(u.y), bf2f(u.z), bf2f(u.w));
            }
            int base = rowptr[n], cnt = rowptr[n + 1] - base;
            float4 a0 = make_float4(0.f, 0.f, 0.f, 0.f), a1 = a0, a2 = a0;
            int i = 0;
            for (; i + 4 <= cnt; i += 4) {
                EDGE_LOAD(0); EDGE_LOAD(1); EDGE_LOAD(2); EDGE_LOAD(3);
                EDGE_FMA(w0, u0); EDGE_FMA(w1, u1);
                EDGE_FMA(w2, u2); EDGE_FMA(w3, u3);
            }
            for (; i < cnt; ++i) {
                EDGE_LOAD(0);
                EDGE_FMA(w0, u0);
            }
            // g[k], k = c*3+d, c = 4cg+u -> k = 12cg+3u+d: 12 contiguous bf16
            unsigned p0 = (unsigned)f2bf(a0.x) | ((unsigned)f2bf(a1.x) << 16);
            unsigned p1 = (unsigned)f2bf(a2.x) | ((unsigned)f2bf(a0.y) << 16);
            unsigned p2 = (unsigned)f2bf(a1.y) | ((unsigned)f2bf(a2.y) << 16);
            unsigned p3 = (unsigned)f2bf(a0.z) | ((unsigned)f2bf(a1.z) << 16);
            unsigned p4 = (unsigned)f2bf(a2.z) | ((unsigned)f2bf(a0.w) << 16);
            unsigned p5 = (unsigned)f2bf(a1.w) | ((unsigned)f2bf(a2.w) << 16);
            uint2* dst = (uint2*)&g_s[j][cg * 12];
            dst[0] = make_uint2(p0, p1);
            dst[1] = make_uint2(p2, p3);
            dst[2] = make_uint2(p4, p5);
        }
    }
    __syncthreads();

    // ---- MFMA phase: 4 waves = 1 mtile x 4 nt-pairs (nh = wave id) ----
    int wv = tid >> 6, ln = tid & 63, lr = ln & 15, lh = ln >> 4;
    int nh = wv;
    bf16x8 a[12];  // A-frags for this block's 16-node mtile, all K
    {
        const ushort* grow = &g_s[lr][0];
        #pragma unroll
        for (int t = 0; t < 12; ++t)
            a[t] = *(const bf16x8*)(grow + t * 32 + lh * 8);
    }
    __syncthreads();  // all A-reads done before h_s (aliasing g_s) is written

    ushort(*h_s)[136] = (ushort(*)[136]) & g_s[0][0];  // 4352 B alias
    const bf16x8* W1f = (const bf16x8*)W1p;
    #pragma unroll
    for (int q = 0; q < 2; ++q) {
        int nt = nh * 2 + q;
        float bb = b1[nt * 16 + lr];
        f32x4 c = {bb, bb, bb, bb};
        #pragma unroll
        for (int t = 0; t < 12; ++t)
            c = __builtin_amdgcn_mfma_f32_16x16x32_bf16(
                a[t], W1f[(nt * 12 + t) * 64 + ln], c, 0, 0, 0);
        #pragma unroll
        for (int r = 0; r < 4; ++r) {
            float x = c[r];
            x = 0.5f * x * (1.0f + erff(x * 0.70710678118654752f));
            h_s[lh * 4 + r][nt * 16 + lr] = f2bf(x);  // row=node, col=mid
        }
    }
    __syncthreads();  // all nt-pairs of h complete

    bf16x8 a2[4];
    {
        const ushort* hrow = &h_s[lr][0];
        #pragma unroll
        for (int t = 0; t < 4; ++t)
            a2[t] = *(const bf16x8*)(hrow + t * 32 + lh * 8);
    }
    const bf16x8* W2f = (const bf16x8*)W2p;
    #pragma unroll
    for (int q = 0; q < 2; ++q) {
        int nt = nh * 2 + q;
        float bb = b2[nt * 16 + lr];
        f32x4 c = {bb, bb, bb, bb};
        #pragma unroll
        for (int t = 0; t < 4; ++t)
            c = __builtin_amdgcn_mfma_f32_16x16x32_bf16(
                a2[t], W2f[(nt * 4 + t) * 64 + ln], c, 0, 0, 0);
        #pragma unroll
        for (int r = 0; r < 4; ++r)
            fo[(size_t)(n0 + lh * 4 + r) * OUT + nt * 16 + lr] = f2bf(c[r]);
    }
}

#define AGG_FMA(K, U)                                                          \
    {                                                                          \
        o.x = fmaf(bf2f(U.x), K.x, o.x); o.y = fmaf(bf2f(U.y), K.x, o.y);      \
        o.z = fmaf(bf2f(U.z), K.x, o.z); o.w = fmaf(bf2f(U.w), K.x, o.w);      \
        den += K.x;                                                            \
    }

// ---------------- edge aggregation (CSR gather) + normalize + fused transpose ----
// R14 per-node loop verbatim; geometry: NTA=32 nodes, 256 threads,
// LDS 16.9KB -> 8 blocks/CU (was 4 at 64-node/512-thread).
__global__ __launch_bounds__(256, 5) void k_agg_t(const ushort* __restrict__ fo,
                                                  const float* __restrict__ nw,
                                                  const int* __restrict__ rowptr,
                                                  const float2* __restrict__ ka2,
                                                  float* __restrict__ out) {
    __shared__ float t[OUT][33];
    __shared__ int ctr;
    int tid = threadIdx.x;
    int cg = tid & 31;
    int cg4 = cg * 4;
    bool lane0 = (cg == 0);
    int bid = blockIdx.x;
    int swz = (bid & 7) * ((B * N / NTA) >> 3) + (bid >> 3);  // XCD swizzle
    int n0 = swz * NTA;               // flat node over B*N
    int b = n0 >> 14, ncol0 = n0 & (N - 1);
    const ushort* fob = fo + (size_t)b * N * OUT;

    if (tid == 0) ctr = 0;
    __syncthreads();

    for (;;) {
        int nl;
        if (lane0) nl = atomicAdd(&ctr, 1);
        nl = __shfl(nl, 0, 32);
        if (nl >= NTA) break;
        int n = n0 + nl;
        int base = rowptr[n], cnt = rowptr[n + 1] - base;
        float4 o = make_float4(0.f, 0.f, 0.f, 0.f);
        float den = 0.f;
        int i = 0;
        for (; i + 4 <= cnt; i += 4) {
            float2 k0 = ka2[base + i];
            float2 k1 = ka2[base + i + 1];
            float2 k2 = ka2[base + i + 2];
            float2 k3 = ka2[base + i + 3];
            ushort4 u0 = *(const ushort4*)(fob + (size_t)__float_as_int(k0.y) * OUT + cg4);
            ushort4 u1 = *(const ushort4*)(fob + (size_t)__float_as_int(k1.y) * OUT + cg4);
            ushort4 u2 = *(const ushort4*)(fob + (size_t)__float_as_int(k2.y) * OUT + cg4);
            ushort4 u3 = *(const ushort4*)(fob + (size_t)__float_as_int(k3.y) * OUT + cg4);
            AGG_FMA(k0, u0);
            AGG_FMA(k1, u1);
            AGG_FMA(k2, u2);
            AGG_FMA(k3, u3);
        }
        for (; i < cnt; ++i) {
            float2 k0 = ka2[base + i];
            ushort4 u0 = *(const ushort4*)(fob + (size_t)__float_as_int(k0.y) * OUT + cg4);
            AGG_FMA(k0, u0);
        }
        float wn = nw[n];  // self edge: d=0 -> kern = nw[n]
        ushort4 uf = *(const ushort4*)(fo + (size_t)n * OUT + cg4);
        float inv = 1.f / (den + wn);
        t[cg4 + 0][nl] = (o.x + bf2f(uf.x) * wn) * inv;
        t[cg4 + 1][nl] = (o.y + bf2f(uf.y) * wn) * inv;
        t[cg4 + 2][nl] = (o.z + bf2f(uf.z) * wn) * inv;
        t[cg4 + 3][nl] = (o.w + bf2f(uf.w) * wn) * inv;
    }
    __syncthreads();
    #pragma unroll
    for (int i = 0; i < 16; ++i) {
        int idx = tid + i * 256;
        int o = idx >> 5, nl = idx & 31;  // nl fastest -> coalesced 128B writes
        out[((size_t)b * OUT + o) * N + ncol0 + nl] = t[o][nl];
    }
}

extern "C" void kernel_launch(void* const* d_in, const int* in_sizes, int n_in,
                              void* d_out, int out_size, void* d_ws, size_t ws_size,
                              hipStream_t stream) {
    const float* f     = (const float*)d_in[0];
    const float* nodes = (const float*)d_in[1];
    const float* nw    = (const float*)d_in[2];
    const int*   ei    = (const int*)d_in[3];
    const float* egw   = (const float*)d_in[4];
    const float* W1    = (const float*)d_in[5];
    const float* b1    = (const float*)d_in[6];
    const float* W2    = (const float*)d_in[7];
    const float* b2    = (const float*)d_in[8];
    const float* L     = (const float*)d_in[9];
    const float* cb    = (const float*)d_in[10];
    float* out = (float*)d_out;

    char* ws = (char*)d_ws;
    auto alloc = [&](size_t bytes) {
        void* p = ws;
        ws += (bytes + 255) & ~(size_t)255;
        return p;
    };
    ushort* fT     = (ushort*)alloc((size_t)B * N * C * 2);
    ushort* fo     = (ushort*)alloc((size_t)B * N * OUT * 2);  // bf16 (R7-proven)
    ushort* W1p    = (ushort*)alloc((size_t)MID * K1 * 2);
    ushort* W2p    = (ushort*)alloc((size_t)OUT * MID * 2);
    float*  Sig    = (float*)alloc(16 * 4);
    int*    deg    = (int*)alloc((size_t)B * N * 4);   // contiguous with cursor:
    int*    cursor = (int*)alloc((size_t)B * N * 4);   // one memset covers both
    int*    rowptr = (int*)alloc(((size_t)B * N + 4) * 4);
    int*    bsum   = (int*)alloc(64 * 4);
    int*    perm   = (int*)alloc((size_t)B * E * 4);
    float4* egwp   = (float4*)alloc((size_t)B * E * 16);
    float2* ka2    = (float2*)alloc((size_t)B * E * 8);

    hipMemsetAsync(deg, 0, (size_t)B * N * 4 * 2, stream);  // deg + cursor

    k_front<<<10304, 256, 0, stream>>>(f, fT, (const int2*)ei, deg, W1, W2, L,
                                       W1p, W2p, Sig);
    k_scan1<<<64, 256, 0, stream>>>((const int4*)deg, rowptr, bsum);
    k_scan2<<<1, 64, 0, stream>>>(bsum, rowptr);
    k_scan3<<<64, 256, 0, stream>>>((int4*)rowptr, bsum);
    k_fill_perm<<<(B * E) / 256, 256, 0, stream>>>((const int2*)ei, rowptr, cursor,
                                                   perm);
    k_fill_expand<<<(B * E) / 256, 256, 0, stream>>>(perm, (const int2*)ei, egw,
                                                     nodes, nw, Sig, cb, egwp, ka2);
    k_grad_mlp<<<(B * N) / NTG, 256, 0, stream>>>(fT, rowptr, egwp, W1p, b1, W2p,
                                                  b2, fo);
    k_agg_t<<<(B * N) / NTA, 256, 0, stream>>>(fo, nw, rowptr, ka2, out);
}